// Round 7
// baseline (256.768 us; speedup 1.0000x reference)
//
#include <hip/hip_runtime.h>
#include <hip/hip_bf16.h>

#define RES 300
#define NPLANE (RES * RES)   // 90000
#define NC_A 48
#define APP_DIM 27
#define KDIM 144             // 3 * NC_A
#define KS 168               // prod LDS row stride in shorts (336 B, 16B-aligned)

#define PCH 384              // p-chunk per prep block (3 scalar loads/thread/ch)
#define NCH 235              // ceil(90000 / 384)
#define NPB3 (3 * NCH)       // 705 plane-transpose blocks

// bf16 (packed in uint halves) -> f32
__device__ __forceinline__ float bf_lo(unsigned int u) { return __uint_as_float(u << 16); }
__device__ __forceinline__ float bf_hi(unsigned int u) { return __uint_as_float(u & 0xffff0000u); }

// ---------------------------------------------------------------------------
// Prep kernel, v2 plane transpose tuned for DRAM row-buffer locality.
//   Old (R1-R6): block = 64 p x 64 ch -> 64 reads of 256 B at 360 KB stride
//   per block; ~130k concurrent 256 B granules over 69 MB -> row-miss per
//   granule -> ~0.9 TB/s, prep ~115 us.
//   New: block = (plane, 384-p chunk). Conversion phase walks channels two
//   at a time reading 1.5 KB CONTIGUOUS per channel (scalar dword, 128-lane
//   dense); LDS tile [384][68 shorts] (pad -> 2-way banks max); write phase
//   emits dense 128 B rows in 4 KB contiguous passes.
//   blocks [705,720): line transpose -> TlP (3,300,64) packed bf16x2 (y,y+1)
//   block  720:       pre-pack MFMA B-fragments of basis_W (bf16, 10 KB)
// ---------------------------------------------------------------------------
__global__ __launch_bounds__(256) void prep(
    const float* __restrict__ plane, const float* __restrict__ line,
    const float* __restrict__ W,
    unsigned int* __restrict__ TpUo, unsigned int* __restrict__ TlP,
    __hip_bfloat16* __restrict__ Wg) {
  __shared__ __align__(16) unsigned short tile[PCH * 68];   // 52,224 B
  const int blk = blockIdx.x;
  const int tid = threadIdx.x;

  if (blk < NPB3) {
    const int i  = blk / NCH;
    const int t0 = blk - i * NCH;
    const int p0 = t0 * PCH;

    const int half = tid >> 7;          // channel parity handled by this thread
    const int pl   = tid & 127;         // p lane within chunk
    const bool ok0 = (p0 + pl)       < NPLANE;
    const bool ok1 = (p0 + pl + 128) < NPLANE;
    const bool ok2 = (p0 + pl + 256) < NPLANE;

    // conversion phase: 32 iterations x 2 channels; 1.5 KB contiguous/channel
    #pragma unroll 2
    for (int cc = 0; cc < 32; ++cc) {
      int c = cc * 2 + half;
      const float* src = plane + (size_t)(i * 64 + c) * NPLANE + p0 + pl;
      float v0 = ok0 ? src[0]   : 0.f;
      float v1 = ok1 ? src[128] : 0.f;
      float v2 = ok2 ? src[256] : 0.f;
      __hip_bfloat16 h0 = __float2bfloat16(v0);
      __hip_bfloat16 h1 = __float2bfloat16(v1);
      __hip_bfloat16 h2 = __float2bfloat16(v2);
      tile[(pl      ) * 68 + c] = *(unsigned short*)&h0;
      tile[(pl + 128) * 68 + c] = *(unsigned short*)&h1;
      tile[(pl + 256) * 68 + c] = *(unsigned short*)&h2;
    }
    __syncthreads();

    // write phase: 12 passes x 32 full 128 B rows (4 KB contiguous per pass)
    const int r = tid & 7, prow = tid >> 3;
    #pragma unroll
    for (int pp = 0; pp < 12; ++pp) {
      int p = pp * 32 + prow;
      if (p0 + p < NPLANE) {
        const unsigned short* row = &tile[p * 68 + r * 8];
        uint4 w;
        w.x = *(const unsigned int*)&row[0];
        w.y = *(const unsigned int*)&row[2];
        w.z = *(const unsigned int*)&row[4];
        w.w = *(const unsigned int*)&row[6];
        *(uint4*)&TpUo[((size_t)(i * NPLANE + p0 + p)) * 32 + r * 4] = w;
      }
    }
  } else if (blk < NPB3 + 15) {
    unsigned int* lt = (unsigned int*)tile;   // 64*65 uints = 16.6 KB, fits
    const int b  = blk - NPB3;
    const int i  = b / 5;
    const int y0 = (b % 5) * 64;
    const int yl = tid & 63;
    const int cq = tid >> 6;
    #pragma unroll
    for (int k = 0; k < 16; ++k) {
      int c = cq * 16 + k;
      int y = y0 + yl;
      float a = 0.f, bv = 0.f;
      if (y < RES) {
        const float* row = line + (i * 64 + c) * RES;
        a  = row[y];
        bv = row[min(y + 1, RES - 1)];
      }
      __hip_bfloat162 h;
      h.x = __float2bfloat16(a);
      h.y = __float2bfloat16(bv);
      lt[yl * 65 + c] = *(unsigned int*)&h;
    }
    __syncthreads();
    #pragma unroll
    for (int k = 0; k < 16; ++k) {
      int ylc = k * 4 + cq;
      int c   = tid & 63;
      int y   = y0 + ylc;
      if (y < RES) TlP[((size_t)i * RES + y) * 64 + c] = lt[ylc * 65 + c];
    }
  } else {
    for (int idx = tid; idx < 2 * 5 * 64 * 8; idx += 256) {
      int j    = idx & 7;
      int lane = (idx >> 3) & 63;
      int kt   = (idx >> 9) % 5;
      int tile_ = idx / (5 * 64 * 8);
      int n = tile_ * 16 + (lane & 15);
      int k = kt * 32 + (lane >> 4) * 8 + j;
      float v = (n < APP_DIM && k < KDIM) ? W[n * KDIM + k] : 0.f;
      Wg[idx] = __float2bfloat16(v);
    }
  }
}

// ---------------------------------------------------------------------------
// Main kernel: UNCHANGED from R6 (passing). Channel-OCTET scheme: lane&7 =
// channel octet, lane>>3 = sample slot -> 8 samples/wave-iter, 2 iterations,
// all-uint4 gathers. Pinned at ~105 us by gather-request throughput (R0-R6
// evidence); left alone this round.
// LDS = 21504 (prod) + 4608 (cw) = 26112 B.
// ---------------------------------------------------------------------------
typedef __attribute__((ext_vector_type(8))) short short8;
typedef __attribute__((ext_vector_type(4))) float f32x4;

__global__ __launch_bounds__(256, 4) void tensorf_main(
    const float* __restrict__ xyz, const unsigned int* __restrict__ TpU,
    const unsigned int* __restrict__ TlP, const __hip_bfloat16* __restrict__ Wg,
    float* __restrict__ out, int n_total) {
  __shared__ __hip_bfloat16 prod[64 * KS];
  __shared__ float cw[64 * 18];

  const int tid  = threadIdx.x;
  const int lane = tid & 63;
  const int wave = tid >> 6;
  const int n0   = blockIdx.x * 64;

  // zero prod k-pad [144,168)
  for (int j = tid; j < 64 * 12; j += 256) {
    int s = j / 12, kk = (j % 12) * 2;
    *(unsigned int*)&prod[s * KS + KDIM + kk] = 0u;
  }

  // Phase 0: per-sample precompute (exact passing R0/R3 form).
  if (tid < 64) {
    int n = min(n0 + tid, n_total - 1);
    float crd[3] = {xyz[3 * n], xyz[3 * n + 1], xyz[3 * n + 2]};
    const int m0s[3] = {0, 0, 1}, m1s[3] = {1, 2, 2}, vms[3] = {2, 1, 0};
    float* c = &cw[tid * 18];
    #pragma unroll
    for (int i = 0; i < 3; ++i) {
      float ix = fminf(fmaxf((crd[m0s[i]] + 1.f) * 149.5f, 0.f), 299.f);
      float iy = fminf(fmaxf((crd[m1s[i]] + 1.f) * 149.5f, 0.f), 299.f);
      float ly = fminf(fmaxf((crd[vms[i]] + 1.f) * 149.5f, 0.f), 299.f);
      float x0f = fminf(floorf(ix), 298.f);
      float y0f = fminf(floorf(iy), 298.f);
      float l0f = fminf(floorf(ly), 298.f);
      float wx = ix - x0f, wy = iy - y0f, lwy = ly - l0f;
      int cell = i * NPLANE + (int)y0f * RES + (int)x0f;   // < 2^19
      int lidx = i * RES + (int)l0f;                       // < 2^10
      c[i * 6 + 0] = __int_as_float(cell | (lidx << 19));
      c[i * 6 + 1] = (1.f - wx) * (1.f - wy);
      c[i * 6 + 2] = wx * (1.f - wy);
      c[i * 6 + 3] = (1.f - wx) * wy;
      c[i * 6 + 4] = wx * wy;
      c[i * 6 + 5] = lwy;
    }
  }
  __syncthreads();

  // Phase 1: 2 iterations, 8 samples/wave-iter, 8 channels/lane, uint4 loads
  const int c8    = lane & 7;   // channel octet -> channels 8c8..8c8+7
  const int sslot = lane >> 3;  // sample slot within iteration group
  const int cu    = c8 * 4;     // uint offset of octet within TpU row

  #pragma unroll
  for (int it = 0; it < 2; ++it) {
    const int s = wave * 16 + it * 8 + sslot;
    const float* cp = &cw[s * 18];

    // batched load phase: 18 x uint4 VMEM (72 dwords) before any use
    unsigned int uc[3][4][4];   // [plane][corner][dword]
    unsigned int uln[3][8];     // [plane][channel-in-octet] line packs
    float wgt[3][5];
    #pragma unroll
    for (int i = 0; i < 3; ++i) {
      float2 q0 = *(const float2*)&cp[i * 6];       // pack, w00
      float2 q1 = *(const float2*)&cp[i * 6 + 2];   // w01, w10
      float2 q2 = *(const float2*)&cp[i * 6 + 4];   // w11, lwy
      int pk   = __float_as_int(q0.x);
      int cell = pk & 0x7FFFF;
      int lidx = pk >> 19;
      int bidx = cell * 32 + cu;                    // uint index into TpU
      *(uint4*)&uc[i][0][0] = *(const uint4*)&TpU[bidx];
      *(uint4*)&uc[i][1][0] = *(const uint4*)&TpU[bidx + 32];
      *(uint4*)&uc[i][2][0] = *(const uint4*)&TpU[bidx + RES * 32];
      *(uint4*)&uc[i][3][0] = *(const uint4*)&TpU[bidx + RES * 32 + 32];
      *(uint4*)&uln[i][0]   = *(const uint4*)&TlP[(lidx << 6) + c8 * 8];
      *(uint4*)&uln[i][4]   = *(const uint4*)&TlP[(lidx << 6) + c8 * 8 + 4];
      wgt[i][0] = q0.y; wgt[i][1] = q1.x; wgt[i][2] = q1.y;
      wgt[i][3] = q2.x; wgt[i][4] = q2.y;
    }

    // blend phase
    float dsum = 0.f;
    #pragma unroll
    for (int i = 0; i < 3; ++i) {
      float w00 = wgt[i][0], w01 = wgt[i][1], w10 = wgt[i][2];
      float w11 = wgt[i][3], lw = wgt[i][4];
      unsigned int res[4];
      #pragma unroll
      for (int d = 0; d < 4; ++d) {   // dword d: channels 8c8+2d, 8c8+2d+1
        float pf_l = w00 * bf_lo(uc[i][0][d]) + w01 * bf_lo(uc[i][1][d]) +
                     w10 * bf_lo(uc[i][2][d]) + w11 * bf_lo(uc[i][3][d]);
        float pf_h = w00 * bf_hi(uc[i][0][d]) + w01 * bf_hi(uc[i][1][d]) +
                     w10 * bf_hi(uc[i][2][d]) + w11 * bf_hi(uc[i][3][d]);
        unsigned int ua = uln[i][2 * d], ub = uln[i][2 * d + 1];
        float lal = bf_lo(ua), lbl = bf_hi(ua);
        float lah = bf_lo(ub), lbh = bf_hi(ub);
        float lf_l = lal + lw * (lbl - lal);
        float lf_h = lah + lw * (lbh - lah);
        float prl = pf_l * lf_l, prh = pf_h * lf_h;
        if (c8 < 6) {
          __hip_bfloat162 h;
          h.x = __float2bfloat16(prl);
          h.y = __float2bfloat16(prh);
          res[d] = *(unsigned int*)&h;
        } else {
          dsum += prl + prh;
        }
      }
      if (c8 < 6) {
        uint4 w4; w4.x = res[0]; w4.y = res[1]; w4.z = res[2]; w4.w = res[3];
        *(uint4*)&prod[s * KS + i * NC_A + c8 * 8] = w4;
      }
    }
    // density reduce: octets 6,7 (lanes differing in bit0 within each slot)
    dsum += __shfl_xor(dsum, 1);
    int n = n0 + s;
    if (c8 == 6 && n < n_total) out[n] = dsum;
  }
  __syncthreads();

  // Phase 2: app = prod(64x144) @ W^T via mfma 16x16x32 bf16, B from Wg
  const int srow = lane & 15, quad = lane >> 4;
  f32x4 acc0 = {0.f, 0.f, 0.f, 0.f}, acc1 = {0.f, 0.f, 0.f, 0.f};
  const short* prodS = (const short*)prod;
  const short* WgS   = (const short*)Wg;
  const int arow = (wave * 16 + srow) * KS;
  #pragma unroll
  for (int kt = 0; kt < 5; ++kt) {
    short8 a  = *(const short8*)&prodS[arow + kt * 32 + quad * 8];
    short8 b0 = *(const short8*)&WgS[(kt * 64 + lane) * 8];
    short8 b1 = *(const short8*)&WgS[((5 + kt) * 64 + lane) * 8];
    acc0 = __builtin_amdgcn_mfma_f32_16x16x32_bf16(a, b0, acc0, 0, 0, 0);
    acc1 = __builtin_amdgcn_mfma_f32_16x16x32_bf16(a, b1, acc1, 0, 0, 0);
  }
  // C/D layout: col(d) = lane&15, row(sample) = quad*4 + reg
  float* outApp = out + n_total;
  #pragma unroll
  for (int r = 0; r < 4; ++r) {
    int n = n0 + wave * 16 + quad * 4 + r;
    if (n < n_total) {
      outApp[(size_t)n * APP_DIM + srow] = acc0[r];
      if (srow < APP_DIM - 16)
        outApp[(size_t)n * APP_DIM + 16 + srow] = acc1[r];
    }
  }
}

// ---------------------------------------------------------------------------
extern "C" void kernel_launch(void* const* d_in, const int* in_sizes, int n_in,
                              void* d_out, int out_size, void* d_ws, size_t ws_size,
                              hipStream_t stream) {
  const float* xyz   = (const float*)d_in[0];
  const float* plane = (const float*)d_in[1];
  const float* line  = (const float*)d_in[2];
  const float* W     = (const float*)d_in[3];
  float* out = (float*)d_out;
  const int N = in_sizes[0] / 3;

  char* ws = (char*)d_ws;
  __hip_bfloat16* Tp  = (__hip_bfloat16*)ws;                        // 34,560,000 B
  unsigned int*   TlP = (unsigned int*)(ws + 34560000);             //    230,400 B
  __hip_bfloat16* Wg  = (__hip_bfloat16*)(ws + 34560000 + 230400);  //     10,240 B

  prep<<<NPB3 + 16, 256, 0, stream>>>(plane, line, W, (unsigned int*)Tp, TlP, Wg);
  tensorf_main<<<(N + 63) / 64, 256, 0, stream>>>(
      xyz, (const unsigned int*)Tp, TlP, Wg, out, N);
}

// Round 8
// 229.939 us; speedup vs baseline: 1.1167x; 1.1167x over previous
//
#include <hip/hip_runtime.h>
#include <hip/hip_bf16.h>

#define RES 300
#define NPLANE (RES * RES)   // 90000
#define NC_A 48
#define APP_DIM 27
#define KDIM 144             // 3 * NC_A
#define KS 168               // prod LDS row stride in shorts (336 B, 16B-aligned)

#define PCH3 256             // p-chunk per prep block
#define NCH3 352             // ceil(90000 / 256)
#define NPB4 (3 * NCH3)      // 1056 plane-transpose blocks
#define PPAD 260             // LDS short stride per channel row (8B-aligned, bank-free)

// bf16 (packed in uint halves) -> f32
__device__ __forceinline__ float bf_lo(unsigned int u) { return __uint_as_float(u << 16); }
__device__ __forceinline__ float bf_hi(unsigned int u) { return __uint_as_float(u & 0xffff0000u); }

// ---------------------------------------------------------------------------
// Prep kernel v3 — streaming-optimal plane transpose.
//   Conversion: wave owns 16 channels; per channel ONE wave-level float4
//   load = 1 KB contiguous; 16 independent loads/thread (deep MLP).
//   LDS tile is channel-major [64][PPAD] shorts: ds_write_b64 8B/thread
//   (bank = 2*lane -> 2-way = free), ds_read_b64 on the way out (free).
//   Write: lane = channel; one wave-inst stores a full 128 B Tp row dense;
//   4 consecutive rows per unrolled group.
//   blocks [1056,1071): line transpose -> TlP (3,300,64) packed bf16x2
//   block  1071:        pre-pack MFMA B-fragments of basis_W (bf16, 10 KB)
// ---------------------------------------------------------------------------
__global__ __launch_bounds__(256) void prep(
    const float* __restrict__ plane, const float* __restrict__ line,
    const float* __restrict__ W,
    unsigned int* __restrict__ TpUo, unsigned int* __restrict__ TlP,
    __hip_bfloat16* __restrict__ Wg) {
  __shared__ __align__(16) unsigned short tileC[64 * PPAD];   // 33,280 B
  const int blk = blockIdx.x;
  const int tid = threadIdx.x;

  if (blk < NPB4) {
    const int i  = blk / NCH3;
    const int t0 = blk - i * NCH3;
    const int p0 = t0 * PCH3;
    const int w  = tid >> 6;    // wave
    const int l  = tid & 63;    // lane

    // conversion: 16 channels per wave, 1 KB contiguous read per channel
    const int pl = 4 * l;                       // p offset of this lane
    const bool okr = (p0 + pl + 3) < NPLANE;    // 90000 % 4 == 0: no straddle
    #pragma unroll 4
    for (int k = 0; k < 16; ++k) {
      int c = w * 16 + k;
      float4 v = make_float4(0.f, 0.f, 0.f, 0.f);
      if (okr) v = *(const float4*)(plane + (size_t)(i * 64 + c) * NPLANE + p0 + pl);
      __hip_bfloat162 ha, hb;
      ha.x = __float2bfloat16(v.x);
      ha.y = __float2bfloat16(v.y);
      hb.x = __float2bfloat16(v.z);
      hb.y = __float2bfloat16(v.w);
      uint2 u;
      u.x = *(unsigned int*)&ha;
      u.y = *(unsigned int*)&hb;
      *(uint2*)&tileC[c * PPAD + pl] = u;       // 8B-aligned, 2-way banks (free)
    }
    __syncthreads();

    // write phase: lane = channel; wave w covers rows w*64..w*64+63
    unsigned short* TpS = (unsigned short*)TpUo;
    #pragma unroll
    for (int rq = 0; rq < 16; ++rq) {
      int pr = w * 64 + rq * 4;                 // 4 rows per ds_read_b64
      uint2 q = *(const uint2*)&tileC[l * PPAD + pr];
      const unsigned short* qs = (const unsigned short*)&q;
      #pragma unroll
      for (int j = 0; j < 4; ++j) {
        int p = pr + j;
        if (p0 + p < NPLANE)
          TpS[((size_t)(i * NPLANE + p0 + p)) * 64 + l] = qs[j];  // 128 B/wave dense
      }
    }
  } else if (blk < NPB4 + 15) {
    unsigned int* lt = (unsigned int*)tileC;    // 64*65 uints = 16,640 B, fits
    const int b  = blk - NPB4;
    const int i  = b / 5;
    const int y0 = (b % 5) * 64;
    const int yl = tid & 63;
    const int cq = tid >> 6;
    #pragma unroll
    for (int k = 0; k < 16; ++k) {
      int c = cq * 16 + k;
      int y = y0 + yl;
      float a = 0.f, bv = 0.f;
      if (y < RES) {
        const float* row = line + (i * 64 + c) * RES;
        a  = row[y];
        bv = row[min(y + 1, RES - 1)];
      }
      __hip_bfloat162 h;
      h.x = __float2bfloat16(a);
      h.y = __float2bfloat16(bv);
      lt[yl * 65 + c] = *(unsigned int*)&h;
    }
    __syncthreads();
    #pragma unroll
    for (int k = 0; k < 16; ++k) {
      int ylc = k * 4 + cq;
      int c   = tid & 63;
      int y   = y0 + ylc;
      if (y < RES) TlP[((size_t)i * RES + y) * 64 + c] = lt[ylc * 65 + c];
    }
  } else {
    for (int idx = tid; idx < 2 * 5 * 64 * 8; idx += 256) {
      int j    = idx & 7;
      int lane = (idx >> 3) & 63;
      int kt   = (idx >> 9) % 5;
      int tile_ = idx / (5 * 64 * 8);
      int n = tile_ * 16 + (lane & 15);
      int k = kt * 32 + (lane >> 4) * 8 + j;
      float v = (n < APP_DIM && k < KDIM) ? W[n * KDIM + k] : 0.f;
      Wg[idx] = __float2bfloat16(v);
    }
  }
}

// ---------------------------------------------------------------------------
// Main kernel: UNCHANGED from R6 (passing, ~105 us). Channel-OCTET scheme:
// lane&7 = channel octet, lane>>3 = sample slot -> 8 samples/wave-iter,
// 2 iterations, all-uint4 gathers. Pinned by gather-request throughput
// (R0-R7 evidence); untouched for clean prep attribution.
// LDS = 21504 (prod) + 4608 (cw) = 26112 B.
// ---------------------------------------------------------------------------
typedef __attribute__((ext_vector_type(8))) short short8;
typedef __attribute__((ext_vector_type(4))) float f32x4;

__global__ __launch_bounds__(256, 4) void tensorf_main(
    const float* __restrict__ xyz, const unsigned int* __restrict__ TpU,
    const unsigned int* __restrict__ TlP, const __hip_bfloat16* __restrict__ Wg,
    float* __restrict__ out, int n_total) {
  __shared__ __hip_bfloat16 prod[64 * KS];
  __shared__ float cw[64 * 18];

  const int tid  = threadIdx.x;
  const int lane = tid & 63;
  const int wave = tid >> 6;
  const int n0   = blockIdx.x * 64;

  // zero prod k-pad [144,168)
  for (int j = tid; j < 64 * 12; j += 256) {
    int s = j / 12, kk = (j % 12) * 2;
    *(unsigned int*)&prod[s * KS + KDIM + kk] = 0u;
  }

  // Phase 0: per-sample precompute (exact passing R0/R3 form).
  if (tid < 64) {
    int n = min(n0 + tid, n_total - 1);
    float crd[3] = {xyz[3 * n], xyz[3 * n + 1], xyz[3 * n + 2]};
    const int m0s[3] = {0, 0, 1}, m1s[3] = {1, 2, 2}, vms[3] = {2, 1, 0};
    float* c = &cw[tid * 18];
    #pragma unroll
    for (int i = 0; i < 3; ++i) {
      float ix = fminf(fmaxf((crd[m0s[i]] + 1.f) * 149.5f, 0.f), 299.f);
      float iy = fminf(fmaxf((crd[m1s[i]] + 1.f) * 149.5f, 0.f), 299.f);
      float ly = fminf(fmaxf((crd[vms[i]] + 1.f) * 149.5f, 0.f), 299.f);
      float x0f = fminf(floorf(ix), 298.f);
      float y0f = fminf(floorf(iy), 298.f);
      float l0f = fminf(floorf(ly), 298.f);
      float wx = ix - x0f, wy = iy - y0f, lwy = ly - l0f;
      int cell = i * NPLANE + (int)y0f * RES + (int)x0f;   // < 2^19
      int lidx = i * RES + (int)l0f;                       // < 2^10
      c[i * 6 + 0] = __int_as_float(cell | (lidx << 19));
      c[i * 6 + 1] = (1.f - wx) * (1.f - wy);
      c[i * 6 + 2] = wx * (1.f - wy);
      c[i * 6 + 3] = (1.f - wx) * wy;
      c[i * 6 + 4] = wx * wy;
      c[i * 6 + 5] = lwy;
    }
  }
  __syncthreads();

  // Phase 1: 2 iterations, 8 samples/wave-iter, 8 channels/lane, uint4 loads
  const int c8    = lane & 7;   // channel octet -> channels 8c8..8c8+7
  const int sslot = lane >> 3;  // sample slot within iteration group
  const int cu    = c8 * 4;     // uint offset of octet within TpU row

  #pragma unroll
  for (int it = 0; it < 2; ++it) {
    const int s = wave * 16 + it * 8 + sslot;
    const float* cp = &cw[s * 18];

    // batched load phase: 18 x uint4 VMEM (72 dwords) before any use
    unsigned int uc[3][4][4];   // [plane][corner][dword]
    unsigned int uln[3][8];     // [plane][channel-in-octet] line packs
    float wgt[3][5];
    #pragma unroll
    for (int i = 0; i < 3; ++i) {
      float2 q0 = *(const float2*)&cp[i * 6];       // pack, w00
      float2 q1 = *(const float2*)&cp[i * 6 + 2];   // w01, w10
      float2 q2 = *(const float2*)&cp[i * 6 + 4];   // w11, lwy
      int pk   = __float_as_int(q0.x);
      int cell = pk & 0x7FFFF;
      int lidx = pk >> 19;
      int bidx = cell * 32 + cu;                    // uint index into TpU
      *(uint4*)&uc[i][0][0] = *(const uint4*)&TpU[bidx];
      *(uint4*)&uc[i][1][0] = *(const uint4*)&TpU[bidx + 32];
      *(uint4*)&uc[i][2][0] = *(const uint4*)&TpU[bidx + RES * 32];
      *(uint4*)&uc[i][3][0] = *(const uint4*)&TpU[bidx + RES * 32 + 32];
      *(uint4*)&uln[i][0]   = *(const uint4*)&TlP[(lidx << 6) + c8 * 8];
      *(uint4*)&uln[i][4]   = *(const uint4*)&TlP[(lidx << 6) + c8 * 8 + 4];
      wgt[i][0] = q0.y; wgt[i][1] = q1.x; wgt[i][2] = q1.y;
      wgt[i][3] = q2.x; wgt[i][4] = q2.y;
    }

    // blend phase
    float dsum = 0.f;
    #pragma unroll
    for (int i = 0; i < 3; ++i) {
      float w00 = wgt[i][0], w01 = wgt[i][1], w10 = wgt[i][2];
      float w11 = wgt[i][3], lw = wgt[i][4];
      unsigned int res[4];
      #pragma unroll
      for (int d = 0; d < 4; ++d) {   // dword d: channels 8c8+2d, 8c8+2d+1
        float pf_l = w00 * bf_lo(uc[i][0][d]) + w01 * bf_lo(uc[i][1][d]) +
                     w10 * bf_lo(uc[i][2][d]) + w11 * bf_lo(uc[i][3][d]);
        float pf_h = w00 * bf_hi(uc[i][0][d]) + w01 * bf_hi(uc[i][1][d]) +
                     w10 * bf_hi(uc[i][2][d]) + w11 * bf_hi(uc[i][3][d]);
        unsigned int ua = uln[i][2 * d], ub = uln[i][2 * d + 1];
        float lal = bf_lo(ua), lbl = bf_hi(ua);
        float lah = bf_lo(ub), lbh = bf_hi(ub);
        float lf_l = lal + lw * (lbl - lal);
        float lf_h = lah + lw * (lbh - lah);
        float prl = pf_l * lf_l, prh = pf_h * lf_h;
        if (c8 < 6) {
          __hip_bfloat162 h;
          h.x = __float2bfloat16(prl);
          h.y = __float2bfloat16(prh);
          res[d] = *(unsigned int*)&h;
        } else {
          dsum += prl + prh;
        }
      }
      if (c8 < 6) {
        uint4 w4; w4.x = res[0]; w4.y = res[1]; w4.z = res[2]; w4.w = res[3];
        *(uint4*)&prod[s * KS + i * NC_A + c8 * 8] = w4;
      }
    }
    // density reduce: octets 6,7 (lanes differing in bit0 within each slot)
    dsum += __shfl_xor(dsum, 1);
    int n = n0 + s;
    if (c8 == 6 && n < n_total) out[n] = dsum;
  }
  __syncthreads();

  // Phase 2: app = prod(64x144) @ W^T via mfma 16x16x32 bf16, B from Wg
  const int srow = lane & 15, quad = lane >> 4;
  f32x4 acc0 = {0.f, 0.f, 0.f, 0.f}, acc1 = {0.f, 0.f, 0.f, 0.f};
  const short* prodS = (const short*)prod;
  const short* WgS   = (const short*)Wg;
  const int arow = (wave * 16 + srow) * KS;
  #pragma unroll
  for (int kt = 0; kt < 5; ++kt) {
    short8 a  = *(const short8*)&prodS[arow + kt * 32 + quad * 8];
    short8 b0 = *(const short8*)&WgS[(kt * 64 + lane) * 8];
    short8 b1 = *(const short8*)&WgS[((5 + kt) * 64 + lane) * 8];
    acc0 = __builtin_amdgcn_mfma_f32_16x16x32_bf16(a, b0, acc0, 0, 0, 0);
    acc1 = __builtin_amdgcn_mfma_f32_16x16x32_bf16(a, b1, acc1, 0, 0, 0);
  }
  // C/D layout: col(d) = lane&15, row(sample) = quad*4 + reg
  float* outApp = out + n_total;
  #pragma unroll
  for (int r = 0; r < 4; ++r) {
    int n = n0 + wave * 16 + quad * 4 + r;
    if (n < n_total) {
      outApp[(size_t)n * APP_DIM + srow] = acc0[r];
      if (srow < APP_DIM - 16)
        outApp[(size_t)n * APP_DIM + 16 + srow] = acc1[r];
    }
  }
}

// ---------------------------------------------------------------------------
extern "C" void kernel_launch(void* const* d_in, const int* in_sizes, int n_in,
                              void* d_out, int out_size, void* d_ws, size_t ws_size,
                              hipStream_t stream) {
  const float* xyz   = (const float*)d_in[0];
  const float* plane = (const float*)d_in[1];
  const float* line  = (const float*)d_in[2];
  const float* W     = (const float*)d_in[3];
  float* out = (float*)d_out;
  const int N = in_sizes[0] / 3;

  char* ws = (char*)d_ws;
  __hip_bfloat16* Tp  = (__hip_bfloat16*)ws;                        // 34,560,000 B
  unsigned int*   TlP = (unsigned int*)(ws + 34560000);             //    230,400 B
  __hip_bfloat16* Wg  = (__hip_bfloat16*)(ws + 34560000 + 230400);  //     10,240 B

  prep<<<NPB4 + 16, 256, 0, stream>>>(plane, line, W, (unsigned int*)Tp, TlP, Wg);
  tensorf_main<<<(N + 63) / 64, 256, 0, stream>>>(
      xyz, (const unsigned int*)Tp, TlP, Wg, out, N);
}